// Round 1
// baseline (316.797 us; speedup 1.0000x reference)
//
#include <hip/hip_runtime.h>
#include <hip/hip_bf16.h>
#include <math.h>

// Problem constants
#define BATCH 64
#define SEQ   512
#define DIM   768
#define NW    256              // MAX_WORDS
#define NT    (BATCH * NW)     // 16384 tokens
#define KDIM  1536             // 2*DIM
#define HID   256              // router hidden
#define NL    7                // num labels

// GEMM tiling
#define BM  32
#define BK  64
#define BKP 72                 // padded LDS row stride (bf16 elems) -> 144 B, breaks bank conflicts
#define NKT (KDIM / BK)        // 24

typedef __bf16 bf16_t;
typedef bf16_t bf16x8 __attribute__((ext_vector_type(8)));
typedef float  f32x4  __attribute__((ext_vector_type(4)));

// ---------------------------------------------------------------------------
// Kernel 1: convert router_w1 (K x H fp32, row-major) into bf16, pre-tiled
// K-major: w1t[kc][n][kk] so each K-step's 32KB B-tile is contiguous.
// ---------------------------------------------------------------------------
__global__ __launch_bounds__(256) void convert_w1_kernel(
    const float* __restrict__ w1, bf16_t* __restrict__ w1t)
{
    int idx = blockIdx.x * 256 + threadIdx.x;      // 24*256*64 = 393216 total
    int kk = idx & 63;
    int n  = (idx >> 6) & 255;
    int kc = idx >> 14;
    w1t[idx] = (bf16_t)w1[(kc * BK + kk) * HID + n];
}

// ---------------------------------------------------------------------------
// Kernel 2: segment-mean align. One block per (b, w). word_ids sorted per row
// -> binary search for the subtoken range. Writes bf16 concat matrix
// X[token][0..767] = mean(hing), X[token][768..1535] = mean(rob).
// ---------------------------------------------------------------------------
__device__ __forceinline__ int lower_bound_512(const int* __restrict__ a, int v)
{
    int lo = 0, hi = SEQ;
    while (lo < hi) { int m = (lo + hi) >> 1; if (a[m] < v) lo = m + 1; else hi = m; }
    return lo;
}

__global__ __launch_bounds__(256) void align_kernel(
    const float* __restrict__ hh, const float* __restrict__ hr,
    const int* __restrict__ idh, const int* __restrict__ idr,
    bf16_t* __restrict__ X)
{
    int blk = blockIdx.x;          // b*NW + w
    int b = blk >> 8;
    int w = blk & 255;
    int tid = threadIdx.x;

    __shared__ int rng[4];
    if (tid == 0) {
        const int* ids = idh + b * SEQ;
        rng[0] = lower_bound_512(ids, w);
        rng[1] = lower_bound_512(ids, w + 1);
    } else if (tid == 64) {
        const int* ids = idr + b * SEQ;
        rng[2] = lower_bound_512(ids, w);
        rng[3] = lower_bound_512(ids, w + 1);
    }
    __syncthreads();
    int loH = rng[0], hiH = rng[1], loR = rng[2], hiR = rng[3];
    float invH = (hiH > loH) ? 1.0f / (float)(hiH - loH) : 0.0f;
    float invR = (hiR > loR) ? 1.0f / (float)(hiR - loR) : 0.0f;

    size_t base = (size_t)b * SEQ * DIM;
    bf16_t* xrow = X + (size_t)blk * KDIM;

    #pragma unroll
    for (int j = 0; j < 3; j++) {
        int d = tid + j * 256;
        float sh = 0.f, sr = 0.f;
        for (int s = loH; s < hiH; s++) sh += hh[base + (size_t)s * DIM + d];
        for (int s = loR; s < hiR; s++) sr += hr[base + (size_t)s * DIM + d];
        xrow[d]       = (bf16_t)(sh * invH);
        xrow[DIM + d] = (bf16_t)(sr * invR);
    }
}

// ---------------------------------------------------------------------------
// Kernel 3: fused router GEMM (bf16 MFMA) + alpha + blend + head + l2.
// Grid: NT/BM = 512 blocks, 256 threads (4 waves).
// Wave wv computes all 32 rows x cols [64*wv, 64*wv+64).
// ---------------------------------------------------------------------------
__global__ __launch_bounds__(256) void gemm_fused_kernel(
    const bf16_t* __restrict__ X, const bf16_t* __restrict__ w1t,
    const float* __restrict__ b1, const float* __restrict__ w2,
    const float* __restrict__ b2, const float* __restrict__ hw,
    const float* __restrict__ hb, float* __restrict__ out)
{
    __shared__ __align__(16) bf16_t Xs[BM][BKP];
    __shared__ __align__(16) bf16_t Ws[HID][BKP];
    __shared__ float alpha_acc[BM];
    __shared__ float alpha_s[BM];

    int tid   = threadIdx.x;
    int lane  = tid & 63;
    int wv    = tid >> 6;
    int row16 = lane & 15;
    int quad  = lane >> 4;
    int blk   = blockIdx.x;
    int tok0  = blk * BM;

    f32x4 acc[2][4];
    #pragma unroll
    for (int mi = 0; mi < 2; mi++)
        #pragma unroll
        for (int ni = 0; ni < 4; ni++)
            acc[mi][ni] = (f32x4){0.f, 0.f, 0.f, 0.f};

    // staging index precompute
    int xr = tid >> 3;   // 0..31 row
    int xc = tid & 7;    // 0..7  16B chunk

    for (int kc = 0; kc < NKT; kc++) {
        // stage X tile: 32 rows x 64 bf16 = 256 chunks of 16B, 1 per thread
        {
            const uint4* src = (const uint4*)(X + (size_t)(tok0 + xr) * KDIM + kc * BK + xc * 8);
            *(uint4*)(&Xs[xr][xc * 8]) = *src;
        }
        // stage W tile: 256 rows(n) x 64 bf16 = 2048 chunks, 8 per thread, coalesced
        {
            const uint4* srcb = (const uint4*)(w1t + (size_t)kc * (HID * BK));
            #pragma unroll
            for (int i = 0; i < 8; i++) {
                int cidx = tid + i * 256;
                int n = cidx >> 3;
                int c = cidx & 7;
                *(uint4*)(&Ws[n][c * 8]) = srcb[cidx];
            }
        }
        __syncthreads();
        #pragma unroll
        for (int kk2 = 0; kk2 < 2; kk2++) {
            bf16x8 af[2], bfg[4];
            #pragma unroll
            for (int mi = 0; mi < 2; mi++)
                af[mi] = *(const bf16x8*)(&Xs[mi * 16 + row16][kk2 * 32 + quad * 8]);
            #pragma unroll
            for (int ni = 0; ni < 4; ni++)
                bfg[ni] = *(const bf16x8*)(&Ws[wv * 64 + ni * 16 + row16][kk2 * 32 + quad * 8]);
            #pragma unroll
            for (int mi = 0; mi < 2; mi++)
                #pragma unroll
                for (int ni = 0; ni < 4; ni++)
                    acc[mi][ni] = __builtin_amdgcn_mfma_f32_16x16x32_bf16(
                        af[mi], bfg[ni], acc[mi][ni], 0, 0, 0);
        }
        __syncthreads();
    }

    // ---- alpha: sigmoid( relu(hdn + b1) . w2 + b2 ) per row --------------
    float w2v[4], b1v[4];
    #pragma unroll
    for (int ni = 0; ni < 4; ni++) {
        int col = wv * 64 + ni * 16 + row16;
        w2v[ni] = w2[col];
        b1v[ni] = b1[col];
    }
    if (tid < BM) alpha_acc[tid] = 0.f;
    __syncthreads();

    #pragma unroll
    for (int mi = 0; mi < 2; mi++) {
        #pragma unroll
        for (int r = 0; r < 4; r++) {
            float p = 0.f;
            #pragma unroll
            for (int ni = 0; ni < 4; ni++) {
                float v = acc[mi][ni][r] + b1v[ni];
                v = v > 0.f ? v : 0.f;
                p += v * w2v[ni];
            }
            // reduce over the 16 col-lanes (xor bits 0..3 stay inside quad)
            p += __shfl_xor(p, 1);
            p += __shfl_xor(p, 2);
            p += __shfl_xor(p, 4);
            p += __shfl_xor(p, 8);
            if (row16 == 0) {
                int rowl = mi * 16 + quad * 4 + r;
                atomicAdd(&alpha_acc[rowl], p);   // 4 waves -> same row
            }
        }
    }
    __syncthreads();
    if (tid < BM) {
        float a = 1.f / (1.f + expf(-(alpha_acc[tid] + b2[0])));
        alpha_s[tid] = a;
        out[(size_t)NT * NL + tok0 + tid] = a;    // alpha output section
    }
    __syncthreads();

    // ---- blend + head logits + l2 norm -----------------------------------
    float* out_logits = out;
    float* out_l2 = out + (size_t)NT * NL + NT;

    #pragma unroll
    for (int i = 0; i < 8; i++) {
        int m = wv * 8 + i;
        int tok = tok0 + m;
        float a = alpha_s[m];
        const bf16_t* xrow = X + (size_t)tok * KDIM;
        float lg[NL] = {0.f, 0.f, 0.f, 0.f, 0.f, 0.f, 0.f};
        float l2p = 0.f;
        #pragma unroll
        for (int j = 0; j < 12; j++) {
            int d = lane + j * 64;
            float hhv = (float)xrow[d];
            float hrv = (float)xrow[DIM + d];
            float bl = a * hhv + (1.f - a) * hrv;
            float df = hhv - hrv;
            l2p += df * df;
            const float* hwd = hw + d * NL;
            #pragma unroll
            for (int l = 0; l < NL; l++) lg[l] += bl * hwd[l];
        }
        #pragma unroll
        for (int off = 1; off < 64; off <<= 1) {
            #pragma unroll
            for (int l = 0; l < NL; l++) lg[l] += __shfl_xor(lg[l], off);
            l2p += __shfl_xor(l2p, off);
        }
        if (lane < NL)       out_logits[(size_t)tok * NL + lane] = lg[lane] + hb[lane];
        else if (lane == NL) out_l2[tok] = sqrtf(l2p);
    }
}

// ---------------------------------------------------------------------------
extern "C" void kernel_launch(void* const* d_in, const int* in_sizes, int n_in,
                              void* d_out, int out_size, void* d_ws, size_t ws_size,
                              hipStream_t stream)
{
    const float* hh  = (const float*)d_in[0];   // h_hing_sub (64,512,768)
    const float* hr  = (const float*)d_in[1];   // h_rob_sub
    const int*   idh = (const int*)d_in[2];     // hing_word_ids (64,512)
    const int*   idr = (const int*)d_in[3];     // rob_word_ids
    // d_in[4] = num_words — unused by the reference outputs
    const float* w1  = (const float*)d_in[5];   // (1536,256)
    const float* b1  = (const float*)d_in[6];   // (256,)
    const float* w2  = (const float*)d_in[7];   // (256,1)
    const float* b2  = (const float*)d_in[8];   // (1,)
    const float* hw  = (const float*)d_in[9];   // (768,7)
    const float* hb  = (const float*)d_in[10];  // (7,)
    float* out = (float*)d_out;

    bf16_t* X   = (bf16_t*)d_ws;                 // NT x 1536 bf16 = 50.3 MB
    bf16_t* w1t = X + (size_t)NT * KDIM;         // 24 x 256 x 64 bf16 = 0.79 MB

    convert_w1_kernel<<<(NKT * HID * BK) / 256, 256, 0, stream>>>(w1, w1t);
    align_kernel<<<NT, 256, 0, stream>>>(hh, hr, idh, idr, X);
    gemm_fused_kernel<<<NT / BM, 256, 0, stream>>>(X, w1t, b1, w2, b2, hw, hb, out);
}

// Round 2
// 297.388 us; speedup vs baseline: 1.0653x; 1.0653x over previous
//
#include <hip/hip_runtime.h>
#include <hip/hip_bf16.h>
#include <math.h>

// Problem constants
#define BATCH 64
#define SEQ   512
#define DIM   768
#define NW    256              // MAX_WORDS
#define NT    (BATCH * NW)     // 16384 tokens
#define KDIM  1536             // 2*DIM
#define HID   256              // router hidden
#define NL    7                // num labels

// GEMM tiling
#define BM  32
#define BK  64
#define BKP 72                 // padded LDS row stride (bf16) -> 144 B; 2-way bank alias max (free)
#define NKT (KDIM / BK)        // 24

typedef __bf16 bf16_t;
typedef bf16_t bf16x4 __attribute__((ext_vector_type(4)));
typedef bf16_t bf16x8 __attribute__((ext_vector_type(8)));
typedef float  f32x4  __attribute__((ext_vector_type(4)));

// ---------------------------------------------------------------------------
// Kernel 1: convert router_w1 (1536 x 256 fp32) -> bf16 K-major tiles
// w1t[kc][n][kk], kc=0..23, n=0..255, kk=0..63.  One block per kc.
// Coalesced global reads -> LDS transpose (stride 257: bank = (k+n)%32, 2-way
// max across a wave = free) -> coalesced 16B tile writes.
// ---------------------------------------------------------------------------
__global__ __launch_bounds__(256) void convert_w1_kernel(
    const float* __restrict__ w1, bf16_t* __restrict__ w1t)
{
    __shared__ float tile[64 * 257];
    int tid = threadIdx.x;
    int kc  = blockIdx.x;

    for (int k = 0; k < 64; k++)                       // coalesced 1KB per iter
        tile[k * 257 + tid] = w1[(size_t)(kc * 64 + k) * HID + tid];
    __syncthreads();

    bf16_t* dst = w1t + (size_t)kc * (HID * BK);
    #pragma unroll
    for (int i = 0; i < 8; i++) {
        int ch = tid + i * 256;                        // 2048 16B chunks
        int n  = ch >> 3;
        int c  = ch & 7;                               // kk chunk of 8
        bf16x8 v;
        #pragma unroll
        for (int j = 0; j < 8; j++)
            v[j] = (bf16_t)tile[(c * 8 + j) * 257 + n];
        *(bf16x8*)(dst + n * BK + c * 8) = v;          // coalesced
    }
}

// ---------------------------------------------------------------------------
// Kernel 2: segment-mean align, latency-optimized.
// Grid 4096 x 256 threads; wave wv handles token blk*4+wv.
// Threads 0..15 do the 8 binary searches (2 tensors x {lo,hi} x 4 words).
// Each lane owns 3 float4 chunks per tensor (6 independent load chains).
// ---------------------------------------------------------------------------
__device__ __forceinline__ int lower_bound_512(const int* __restrict__ a, int v)
{
    int lo = 0, hi = SEQ;
    while (lo < hi) { int m = (lo + hi) >> 1; if (a[m] < v) lo = m + 1; else hi = m; }
    return lo;
}

__global__ __launch_bounds__(256) void align_kernel(
    const float* __restrict__ hh, const float* __restrict__ hr,
    const int* __restrict__ idh, const int* __restrict__ idr,
    bf16_t* __restrict__ X)
{
    __shared__ int rngS[16];
    int tid  = threadIdx.x;
    int lane = tid & 63;
    int wv   = tid >> 6;

    if (tid < 16) {
        int tsub  = tid >> 2;
        int which = (tid >> 1) & 1;                    // 0=hing, 1=rob
        int bound = tid & 1;                           // 0=lo, 1=hi
        int tok   = blockIdx.x * 4 + tsub;
        int b     = tok >> 8;
        int w     = tok & 255;
        const int* ids = (which ? idr : idh) + b * SEQ;
        rngS[tid] = lower_bound_512(ids, w + bound);
    }
    __syncthreads();

    int tok = blockIdx.x * 4 + wv;
    int b   = tok >> 8;
    int loH = rngS[wv * 4 + 0], hiH = rngS[wv * 4 + 1];
    int loR = rngS[wv * 4 + 2], hiR = rngS[wv * 4 + 3];

    const f32x4* baseH = (const f32x4*)(hh + (size_t)b * SEQ * DIM);
    const f32x4* baseR = (const f32x4*)(hr + (size_t)b * SEQ * DIM);

    f32x4 aH0 = {0,0,0,0}, aH1 = {0,0,0,0}, aH2 = {0,0,0,0};
    f32x4 aR0 = {0,0,0,0}, aR1 = {0,0,0,0}, aR2 = {0,0,0,0};

    for (int s = loH; s < hiH; s++) {
        const f32x4* row = baseH + (size_t)s * (DIM / 4);
        aH0 += row[lane]; aH1 += row[lane + 64]; aH2 += row[lane + 128];
    }
    for (int s = loR; s < hiR; s++) {
        const f32x4* row = baseR + (size_t)s * (DIM / 4);
        aR0 += row[lane]; aR1 += row[lane + 64]; aR2 += row[lane + 128];
    }

    float invH = (hiH > loH) ? 1.0f / (float)(hiH - loH) : 0.0f;
    float invR = (hiR > loR) ? 1.0f / (float)(hiR - loR) : 0.0f;

    bf16_t* xrow = X + (size_t)tok * KDIM;
    f32x4 accs[6] = {aH0, aH1, aH2, aR0, aR1, aR2};
    #pragma unroll
    for (int c = 0; c < 6; c++) {
        float inv = (c < 3) ? invH : invR;
        int   d0  = (c < 3) ? (lane + 64 * c) * 4 : DIM + (lane + 64 * (c - 3)) * 4;
        bf16x4 o;
        #pragma unroll
        for (int e = 0; e < 4; e++) o[e] = (bf16_t)(accs[c][e] * inv);
        *(bf16x4*)(xrow + d0) = o;                     // 8B store, coalesced per wave
    }
}

// ---------------------------------------------------------------------------
// Kernel 3: router GEMM (bf16 MFMA) -> alpha only.
// Grid NT/BM = 512 blocks x 256 threads (4 waves). Wave wv: 32 rows x cols
// [64*wv, 64*wv+64). 16x16x32 MFMA; A m=lane&15,k=quad*8+j; C col=lane&15,
// row=quad*4+reg.
// ---------------------------------------------------------------------------
__global__ __launch_bounds__(256) void gemm_alpha_kernel(
    const bf16_t* __restrict__ X, const bf16_t* __restrict__ w1t,
    const float* __restrict__ b1, const float* __restrict__ w2,
    const float* __restrict__ b2, float* __restrict__ out)
{
    __shared__ __align__(16) bf16_t Xs[BM][BKP];
    __shared__ __align__(16) bf16_t Ws[HID][BKP];
    __shared__ float alpha_acc[BM];

    int tid   = threadIdx.x;
    int lane  = tid & 63;
    int wv    = tid >> 6;
    int row16 = lane & 15;
    int quad  = lane >> 4;
    int tok0  = blockIdx.x * BM;

    f32x4 acc[2][4];
    #pragma unroll
    for (int mi = 0; mi < 2; mi++)
        #pragma unroll
        for (int ni = 0; ni < 4; ni++)
            acc[mi][ni] = (f32x4){0.f, 0.f, 0.f, 0.f};

    int xr = tid >> 3;   // 0..31
    int xc = tid & 7;    // 0..7

    for (int kc = 0; kc < NKT; kc++) {
        {   // X tile: 32 x 64 bf16, one 16B chunk per thread
            const uint4* src = (const uint4*)(X + (size_t)(tok0 + xr) * KDIM + kc * BK + xc * 8);
            *(uint4*)(&Xs[xr][xc * 8]) = *src;
        }
        {   // W tile: 256 x 64 bf16, 8 16B chunks per thread, coalesced
            const uint4* srcb = (const uint4*)(w1t + (size_t)kc * (HID * BK));
            #pragma unroll
            for (int i = 0; i < 8; i++) {
                int cidx = tid + i * 256;
                *(uint4*)(&Ws[cidx >> 3][(cidx & 7) * 8]) = srcb[cidx];
            }
        }
        __syncthreads();
        #pragma unroll
        for (int kk2 = 0; kk2 < 2; kk2++) {
            bf16x8 af[2], bfg[4];
            #pragma unroll
            for (int mi = 0; mi < 2; mi++)
                af[mi] = *(const bf16x8*)(&Xs[mi * 16 + row16][kk2 * 32 + quad * 8]);
            #pragma unroll
            for (int ni = 0; ni < 4; ni++)
                bfg[ni] = *(const bf16x8*)(&Ws[wv * 64 + ni * 16 + row16][kk2 * 32 + quad * 8]);
            #pragma unroll
            for (int mi = 0; mi < 2; mi++)
                #pragma unroll
                for (int ni = 0; ni < 4; ni++)
                    acc[mi][ni] = __builtin_amdgcn_mfma_f32_16x16x32_bf16(
                        af[mi], bfg[ni], acc[mi][ni], 0, 0, 0);
        }
        __syncthreads();
    }

    // alpha = sigmoid( relu(hdn + b1) . w2 + b2 )
    float w2v[4], b1v[4];
    #pragma unroll
    for (int ni = 0; ni < 4; ni++) {
        int col = wv * 64 + ni * 16 + row16;
        w2v[ni] = w2[col];
        b1v[ni] = b1[col];
    }
    if (tid < BM) alpha_acc[tid] = 0.f;
    __syncthreads();

    #pragma unroll
    for (int mi = 0; mi < 2; mi++) {
        #pragma unroll
        for (int r = 0; r < 4; r++) {
            float p = 0.f;
            #pragma unroll
            for (int ni = 0; ni < 4; ni++) {
                float v = acc[mi][ni][r] + b1v[ni];
                v = v > 0.f ? v : 0.f;
                p += v * w2v[ni];
            }
            p += __shfl_xor(p, 1);
            p += __shfl_xor(p, 2);
            p += __shfl_xor(p, 4);
            p += __shfl_xor(p, 8);
            if (row16 == 0)
                atomicAdd(&alpha_acc[mi * 16 + quad * 4 + r], p);
        }
    }
    __syncthreads();
    if (tid < BM) {
        float a = 1.f / (1.f + expf(-(alpha_acc[tid] + b2[0])));
        out[(size_t)NT * NL + tok0 + tid] = a;
    }
}

// ---------------------------------------------------------------------------
// Kernel 4: blend + head logits + l2.  Wave per token, grid 4096 x 256.
// X reads bf16x4; hw reads f32x4 (28 floats per 4-d group, 16B aligned).
// ---------------------------------------------------------------------------
__global__ __launch_bounds__(256) void blend_kernel(
    const bf16_t* __restrict__ X, const float* __restrict__ hw,
    const float* __restrict__ hb, float* __restrict__ out)
{
    int tid  = threadIdx.x;
    int lane = tid & 63;
    int wv   = tid >> 6;
    int tok  = blockIdx.x * 4 + wv;

    const float* alpha = out + (size_t)NT * NL;
    float a = alpha[tok];
    const bf16_t* xrow = X + (size_t)tok * KDIM;

    float lg[NL] = {0.f, 0.f, 0.f, 0.f, 0.f, 0.f, 0.f};
    float l2 = 0.f;

    #pragma unroll
    for (int j = 0; j < 3; j++) {
        int d0 = (lane + 64 * j) * 4;
        bf16x4 hp = *(const bf16x4*)(xrow + d0);
        bf16x4 rp = *(const bf16x4*)(xrow + DIM + d0);
        const f32x4* hwv = (const f32x4*)(hw + (size_t)d0 * NL);  // 28 floats = 7 vec4
        f32x4 wv4[7];
        #pragma unroll
        for (int q = 0; q < 7; q++) wv4[q] = hwv[q];
        #pragma unroll
        for (int e = 0; e < 4; e++) {
            float hhv = (float)hp[e];
            float hrv = (float)rp[e];
            float bl  = a * hhv + (1.f - a) * hrv;
            float df  = hhv - hrv;
            l2 += df * df;
            #pragma unroll
            for (int l = 0; l < NL; l++) {
                int idx = e * NL + l;
                lg[l] += bl * wv4[idx >> 2][idx & 3];
            }
        }
    }

    #pragma unroll
    for (int off = 1; off < 64; off <<= 1) {
        #pragma unroll
        for (int l = 0; l < NL; l++) lg[l] += __shfl_xor(lg[l], off);
        l2 += __shfl_xor(l2, off);
    }

    if (lane < NL)
        out[(size_t)tok * NL + lane] = lg[lane] + hb[lane];
    else if (lane == NL)
        out[(size_t)NT * NL + NT + tok] = sqrtf(l2);
}

// ---------------------------------------------------------------------------
extern "C" void kernel_launch(void* const* d_in, const int* in_sizes, int n_in,
                              void* d_out, int out_size, void* d_ws, size_t ws_size,
                              hipStream_t stream)
{
    const float* hh  = (const float*)d_in[0];   // (64,512,768)
    const float* hr  = (const float*)d_in[1];
    const int*   idh = (const int*)d_in[2];     // (64,512) sorted
    const int*   idr = (const int*)d_in[3];
    // d_in[4] = num_words (unused)
    const float* w1  = (const float*)d_in[5];   // (1536,256)
    const float* b1  = (const float*)d_in[6];
    const float* w2  = (const float*)d_in[7];   // (256,1)
    const float* b2  = (const float*)d_in[8];
    const float* hw  = (const float*)d_in[9];   // (768,7)
    const float* hb  = (const float*)d_in[10];
    float* out = (float*)d_out;

    bf16_t* X   = (bf16_t*)d_ws;                 // NT x 1536 bf16 = 50.3 MB
    bf16_t* w1t = X + (size_t)NT * KDIM;         // 0.79 MB

    convert_w1_kernel<<<NKT, 256, 0, stream>>>(w1, w1t);
    align_kernel<<<NT / 4, 256, 0, stream>>>(hh, hr, idh, idr, X);
    gemm_alpha_kernel<<<NT / BM, 256, 0, stream>>>(X, w1t, b1, w2, b2, out);
    blend_kernel<<<NT / 4, 256, 0, stream>>>(X, hw, hb, out);
}